// Round 9
// baseline (581.216 us; speedup 1.0000x reference)
//
#include <hip/hip_runtime.h>
#include <hip/hip_bf16.h>

#define NUM_GENES 4384
#define GPAD 4608        // 18 * 256 (pad resident dim; 256 rows per block)
#define DM 128
#define ROWB 256         // bytes per bf16 row (128*2)
#define LDS_STRIDE 272   // 256 + 16B pad (b128 4-way = data floor)
#define NTILES 137       // 4384 / 32
#define RB_BLOCKS 18
#define NCHUNK 6
#define TPC 23           // 5 chunks of 23 + 1 of 22
#define TOTAL_BLK 864u   // 18 * 6 * 8 <= 256 CU * 4 blocks (launch_bounds contract)

typedef __attribute__((ext_vector_type(8))) short short8;
typedef __attribute__((ext_vector_type(16))) float floatx16;

#if defined(__has_builtin)
#  if __has_builtin(__builtin_amdgcn_exp2f)
#    define FAST_EXP2(x) __builtin_amdgcn_exp2f(x)
#  endif
#endif
#ifndef FAST_EXP2
#  define FAST_EXP2(x) exp2f(x)
#endif

static __device__ __forceinline__ short bf16bits(float x) {
    __hip_bfloat16 h = __float2bfloat16(x);
    return *(short*)&h;
}

// Fused prep, 8 outputs/thread, 16B stores.
// Q: blocks [0,2304)  K: [2304,2592)  zero l/w/cnt: [2592,2610)
__global__ __launch_bounds__(256)
void prep_all(const float* __restrict__ mut, const float* __restrict__ W_in,
              const float* __restrict__ b_in, const float* __restrict__ key,
              __hip_bfloat16* __restrict__ Qb, __hip_bfloat16* __restrict__ Kb,
              float* __restrict__ l, float* __restrict__ w,
              unsigned* __restrict__ cnt) {
    int bx = blockIdx.x, t = threadIdx.x;
    if (bx < 2304) {                        // Q: 8*4608*128 elems, 8 per thread
        int i = bx * 256 + t;               // [0, 589824)
        int d0 = (i & 15) * 8;
        int g = (i >> 4) % GPAD;
        int b = i / (GPAD * 16);
        short8 o;
        if (g < NUM_GENES) {
            const float4 mv = *(const float4*)(mut + ((size_t)b * NUM_GENES + g) * 4);
            const float sc = 0.08838834764831845f * 1.4426950408889634f; // 1/sqrt(128)*log2(e)
#pragma unroll
            for (int j = 0; j < 8; ++j) {
                int d = d0 + j;
                float v = b_in[d] + mv.x * W_in[d] + mv.y * W_in[128 + d]
                                  + mv.z * W_in[256 + d] + mv.w * W_in[384 + d];
                o[j] = bf16bits(v * sc);
            }
        } else {
#pragma unroll
            for (int j = 0; j < 8; ++j) o[j] = 0;
        }
        *(short8*)((short*)Qb + (size_t)i * 8) = o;
    } else if (bx < 2592) {                 // K: 4608*128 elems, 8 per thread
        int i = (bx - 2304) * 256 + t;      // [0, 73728)
        int g = i >> 4;
        short8 o;
        if (g < NUM_GENES) {
            const float4 k0 = *(const float4*)(key + (size_t)i * 8);
            const float4 k1 = *(const float4*)(key + (size_t)i * 8 + 4);
            o[0] = bf16bits(k0.x); o[1] = bf16bits(k0.y);
            o[2] = bf16bits(k0.z); o[3] = bf16bits(k0.w);
            o[4] = bf16bits(k1.x); o[5] = bf16bits(k1.y);
            o[6] = bf16bits(k1.z); o[7] = bf16bits(k1.w);
        } else {
#pragma unroll
            for (int j = 0; j < 8; ++j) o[j] = 0;
        }
        *(short8*)((short*)Kb + (size_t)i * 8) = o;
    } else {                                // zero: 18 blocks cover l,w (36864 floats each)
        int i = (bx - 2592) * 256 + t;      // [0, 4608)
        float4 z = {0.f, 0.f, 0.f, 0.f};
        *(float4*)(l + (size_t)i * 8) = z;
        *(float4*)(l + (size_t)i * 8 + 4) = z;
        *(float4*)(w + (size_t)i * 8) = z;
        *(float4*)(w + (size_t)i * 8 + 4) = z;
        if (bx == 2592 && t < 4) cnt[t] = 0u;
    }
}

// Grid barrier: release add, relaxed polls (no L2 inv per poll), one acquire at exit.
// Safe because TOTAL_BLK (864) <= co-resident capacity (4 blocks/CU * 256, enforced
// by __launch_bounds__(256,4)).
static __device__ __forceinline__ void gsync(unsigned* c, int t) {
    __syncthreads();
    if (t == 0) {
        __hip_atomic_fetch_add(c, 1u, __ATOMIC_RELEASE, __HIP_MEMORY_SCOPE_AGENT);
        int guard = 0;
        while (__hip_atomic_load(c, __ATOMIC_RELAXED, __HIP_MEMORY_SCOPE_AGENT) < TOTAL_BLK
               && guard < (1 << 24)) {
            __builtin_amdgcn_s_sleep(1);
            ++guard;
        }
        (void)__hip_atomic_load(c, __ATOMIC_ACQUIRE, __HIP_MEMORY_SCOPE_AGENT);
    }
    __syncthreads();
}

// R5-verbatim phase body (62.6 us form). PB=false: resident=Q(b), stream=K,
// epilogue atomicAdd rowsums->lbuf. PB=true: resident=K, stream=Q(b), scale by
// 1/l (agent atomic load: l written by phase A in the same launch).
// A/B frag: lane row/col (lane&31), 16B at byte dsl*32+(lane>>5)*16.
// C/D: col=lane&31, row=(r&3)+8*(r>>2)+4*(lane>>5).
template <bool PB>
static __device__ __forceinline__
void phase_body(int rb, int chunk, int b, int t,
                const __hip_bfloat16* Qb, const __hip_bfloat16* Kb,
                const float* lsum, float* outv, char* tileraw) {
    char (*tile)[32 * LDS_STRIDE] = (char (*)[32 * LDS_STRIDE])tileraw;

    const char* resident = (const char*)(PB ? Kb : (Qb + (size_t)b * GPAD * DM));
    const char* stream   = (const char*)(PB ? (Qb + (size_t)b * GPAD * DM) : Kb);

    int lane = t & 63, wid = t >> 6;
    int m = lane & 31, half = lane >> 5;

    short8 afrag[2][8];
#pragma unroll
    for (int g = 0; g < 2; ++g) {
        const char* arow = resident + (size_t)(rb * 256 + wid * 64 + g * 32 + m) * ROWB;
#pragma unroll
        for (int dsl = 0; dsl < 8; ++dsl)
            afrag[g][dsl] = *(const short8*)(arow + dsl * 32 + half * 16);
    }

    float lacc[2][16];
#pragma unroll
    for (int g = 0; g < 2; ++g)
#pragma unroll
        for (int r = 0; r < 16; ++r) lacc[g][r] = 0.f;

    int t0 = chunk * TPC;
    int t1 = min(NTILES, t0 + TPC);
    int sr = t >> 3, sc = t & 7;
    int soff = sr * LDS_STRIDE + sc * 32;

    {
        const char* src = stream + (size_t)(t0 * 32 + sr) * ROWB + sc * 32;
        float4 v0 = *(const float4*)src;
        float4 v1 = *(const float4*)(src + 16);
        *(float4*)(tile[0] + soff) = v0;
        *(float4*)(tile[0] + soff + 16) = v1;
    }

    int p = 0;
    for (int kt = t0; kt < t1; ++kt) {
        bool more = (kt + 1 < t1);
        float4 v0, v1;
        if (more) {
            const char* s2 = stream + (size_t)((kt + 1) * 32 + sr) * ROWB + sc * 32;
            v0 = *(const float4*)s2;
            v1 = *(const float4*)(s2 + 16);
        }
        __syncthreads();

        floatx16 acc0, acc1;
#pragma unroll
        for (int r = 0; r < 16; ++r) { acc0[r] = 0.f; acc1[r] = 0.f; }
#pragma unroll
        for (int dsl = 0; dsl < 8; ++dsl) {
            short8 bfrag = *(const short8*)(tile[p] + m * LDS_STRIDE + dsl * 32 + half * 16);
            acc0 = __builtin_amdgcn_mfma_f32_32x32x16_bf16(afrag[0][dsl], bfrag, acc0, 0, 0, 0);
            acc1 = __builtin_amdgcn_mfma_f32_32x32x16_bf16(afrag[1][dsl], bfrag, acc1, 0, 0, 0);
        }

        if (more) {
            *(float4*)(tile[p ^ 1] + soff) = v0;
            *(float4*)(tile[p ^ 1] + soff + 16) = v1;
        }

        if (PB) {
            float lv = __hip_atomic_load(lsum + b * GPAD + kt * 32 + m,
                                         __ATOMIC_RELAXED, __HIP_MEMORY_SCOPE_AGENT);
            float scl = __builtin_amdgcn_rcpf(lv);
#pragma unroll
            for (int r = 0; r < 16; ++r) {
                lacc[0][r] = fmaf(FAST_EXP2(acc0[r]), scl, lacc[0][r]);
                lacc[1][r] = fmaf(FAST_EXP2(acc1[r]), scl, lacc[1][r]);
            }
        } else {
#pragma unroll
            for (int r = 0; r < 16; ++r) {
                lacc[0][r] += FAST_EXP2(acc0[r]);
                lacc[1][r] += FAST_EXP2(acc1[r]);
            }
        }
        p ^= 1;
    }

#pragma unroll
    for (int off = 1; off <= 16; off <<= 1)
#pragma unroll
        for (int g = 0; g < 2; ++g)
#pragma unroll
            for (int r = 0; r < 16; ++r)
                lacc[g][r] += __shfl_xor(lacc[g][r], off, 64);

    if (m == 0) {   // lanes 0 and 32 hold sums for rows (+0 / +4); 32 atomics/block
#pragma unroll
        for (int g = 0; g < 2; ++g) {
            float* ob = outv + b * GPAD + rb * 256 + wid * 64 + g * 32 + 4 * half;
#pragma unroll
            for (int r = 0; r < 16; ++r)
                atomicAdd(ob + (r & 3) + 8 * (r >> 2), lacc[g][r]);
        }
    }
}

// Single launch: phase A -> gsync -> phase B -> gsync -> mean partials (private
// slots, no contended atomics) -> gsync -> reduce (8 blocks) -> gsync -> MLP (block 0).
__global__ __launch_bounds__(256, 4)
void fused_attn(const __hip_bfloat16* __restrict__ Qb,
                const __hip_bfloat16* __restrict__ Kb,
                float* __restrict__ lbuf, float* __restrict__ wbuf,
                float* __restrict__ partial,   // [108][8][128] (aliases Qb; dead by then)
                float* __restrict__ meanbuf,
                const float* __restrict__ V,
                const float* __restrict__ W1, const float* __restrict__ b1,
                const float* __restrict__ W2, const float* __restrict__ b2,
                float* __restrict__ out, unsigned* __restrict__ cnt) {
    __shared__ __align__(16) char tile[2 * 32 * LDS_STRIDE];
    __shared__ float red[256];
    __shared__ float smean[1024];
    __shared__ float shh[512];

    int rb = blockIdx.x, chunk = blockIdx.y, b = blockIdx.z;
    int t = threadIdx.x;
    int bid = rb + RB_BLOCKS * (chunk + NCHUNK * b);   // 0..863

    phase_body<false>(rb, chunk, b, t, Qb, Kb, nullptr, lbuf, tile);
    gsync(cnt + 0, t);
    phase_body<true>(rb, chunk, b, t, Qb, Kb, lbuf, wbuf, tile);
    gsync(cnt + 1, t);

    // mean partials: slice s of 43 gene rows for batch bb -> private slot
    {
        int s = bid % 108, bb = bid / 108;
        int g0 = s * 43;
        int cr = NUM_GENES - g0;
        if (cr > 43) cr = 43;
        int d = t & 127, hf = t >> 7;
        float a = 0.f;
        if (cr > 0) {
            const float* wp = wbuf + bb * GPAD + g0;
            const float* Vp = V + (size_t)g0 * 128 + d;
            for (int k = hf; k < cr; k += 2)
                a += wp[k] * Vp[(size_t)k * 128];
        }
        red[t] = a;
        __syncthreads();
        if (t < 128)
            partial[((size_t)s * 8 + bb) * 128 + t] = red[t] + red[t + 128];
    }
    gsync(cnt + 2, t);

    // reduce 108 slices -> meanbuf (scaled by 1/G); blocks 0..7
    if (bid < 8) {
        int d = t & 127, hf = t >> 7;
        float a = 0.f;
        for (int s = hf; s < 108; s += 2)
            a += partial[((size_t)s * 8 + bid) * 128 + d];
        __syncthreads();   // red[] reuse safe (prior stage consumers done in-block)
        red[t] = a;
        __syncthreads();
        if (t < 128)
            meanbuf[bid * 128 + t] = (red[t] + red[t + 128]) * (1.0f / 4384.0f);
    }
    gsync(cnt + 3, t);

    // MLP: block 0 only (R7-verified tail, minus fences)
    if (bid == 0) {
        for (int i = t; i < 1024; i += 256) smean[i] = meanbuf[i];
        __syncthreads();
        for (int pair = t; pair < 512; pair += 256) {
            int bb = pair >> 6, h = pair & 63;
            const float* mb = smean + bb * 128;
            float s = b1[h];
            for (int d = 0; d < 128; ++d)
                s += mb[d] * W1[d * 64 + h];
            shh[pair] = 0.5f * s * (1.0f + erff(s * 0.70710678118654752f)); // exact gelu
        }
        __syncthreads();
        if (t < 208) {                  // 8 batches * 26 outputs
            int bb = t / 26, j = t % 26;
            const float* hp = shh + bb * 64;
            float o = b2[j];
            for (int k = 0; k < 64; ++k) o += hp[k] * W2[k * 26 + j];
            out[bb * 26 + j] = o;
        }
    }
}

extern "C" void kernel_launch(void* const* d_in, const int* in_sizes, int n_in,
                              void* d_out, int out_size, void* d_ws, size_t ws_size,
                              hipStream_t stream) {
    const float* mut  = (const float*)d_in[0];   // [8,4384,4]
    const float* V    = (const float*)d_in[1];   // [4384,128]
    const float* W_in = (const float*)d_in[2];   // [4,128]
    const float* b_in = (const float*)d_in[3];   // [128]
    const float* key  = (const float*)d_in[4];   // [4384,128]
    const float* W1   = (const float*)d_in[5];   // [128,64]
    const float* b1   = (const float*)d_in[6];   // [64]
    const float* W2   = (const float*)d_in[7];   // [64,26]
    const float* b2   = (const float*)d_in[8];   // [26]
    float* out = (float*)d_out;                  // [8,26]

    char* ws = (char*)d_ws;
    __hip_bfloat16* Qb = (__hip_bfloat16*)(ws);                    // 9,437,184
    __hip_bfloat16* Kb = (__hip_bfloat16*)(ws + 9437184);          // 1,179,648
    float* lbuf        = (float*)(ws + 10616832);                  //   147,456
    float* wbuf        = (float*)(ws + 10764288);                  //   147,456
    float* meanbuf     = (float*)(ws + 10911744);                  //     4,096
    unsigned* cnt      = (unsigned*)(ws + 10915840);               //        16
    float* partial     = (float*)(ws);   // aliases Qb: Qb dead after phase B

    prep_all<<<2610, 256, 0, stream>>>(mut, W_in, b_in, key, Qb, Kb, lbuf, wbuf, cnt);

    dim3 grid(RB_BLOCKS, NCHUNK, 8);
    fused_attn<<<grid, 256, 0, stream>>>(Qb, Kb, lbuf, wbuf, partial, meanbuf,
                                         V, W1, b1, W2, b2, out, cnt);
}

// Round 10
// 216.549 us; speedup vs baseline: 2.6840x; 2.6840x over previous
//
#include <hip/hip_runtime.h>
#include <hip/hip_bf16.h>

#define NUM_GENES 4384
#define GPAD 4608        // 18 * 256 (pad resident dim; 256 rows per block)
#define DM 128
#define ROWB 256         // bytes per bf16 row (128*2)
#define LDS_STRIDE 272   // 256 + 16B pad (b128 4-way = data floor, not a real conflict)
#define NTILES 137       // 4384 / 32
#define RB_BLOCKS 18
#define NCHUNK 6
#define TPC 23           // 5 chunks of 23 + 1 of 22
#define MEAN_BLOCKS 280u // 35 * 8

typedef __attribute__((ext_vector_type(8))) short short8;
typedef __attribute__((ext_vector_type(16))) float floatx16;

#if defined(__has_builtin)
#  if __has_builtin(__builtin_amdgcn_exp2f)
#    define FAST_EXP2(x) __builtin_amdgcn_exp2f(x)
#  endif
#endif
#ifndef FAST_EXP2
#  define FAST_EXP2(x) exp2f(x)
#endif

static __device__ __forceinline__ short bf16bits(float x) {
    __hip_bfloat16 h = __float2bfloat16(x);
    return *(short*)&h;
}

// Fused prep, 8 outputs/thread, 16B stores.  (R5 verbatim + donecnt zero)
// Q: blocks [0,2304)  K: [2304,2592)  zero l/w/mean/cnt: [2592,2610)
__global__ __launch_bounds__(256)
void prep_all(const float* __restrict__ mut, const float* __restrict__ W_in,
              const float* __restrict__ b_in, const float* __restrict__ key,
              __hip_bfloat16* __restrict__ Qb, __hip_bfloat16* __restrict__ Kb,
              float* __restrict__ l, float* __restrict__ w,
              float* __restrict__ meanbuf, unsigned* __restrict__ donecnt) {
    int bx = blockIdx.x, t = threadIdx.x;
    if (bx < 2304) {                        // Q: 8*4608*128 elems, 8 per thread
        int i = bx * 256 + t;               // [0, 589824)
        int d0 = (i & 15) * 8;
        int g = (i >> 4) % GPAD;
        int b = i / (GPAD * 16);
        short8 o;
        if (g < NUM_GENES) {
            const float4 mv = *(const float4*)(mut + ((size_t)b * NUM_GENES + g) * 4);
            const float sc = 0.08838834764831845f * 1.4426950408889634f; // 1/sqrt(128)*log2(e)
#pragma unroll
            for (int j = 0; j < 8; ++j) {
                int d = d0 + j;
                float v = b_in[d] + mv.x * W_in[d] + mv.y * W_in[128 + d]
                                  + mv.z * W_in[256 + d] + mv.w * W_in[384 + d];
                o[j] = bf16bits(v * sc);
            }
        } else {
#pragma unroll
            for (int j = 0; j < 8; ++j) o[j] = 0;
        }
        *(short8*)((short*)Qb + (size_t)i * 8) = o;
    } else if (bx < 2592) {                 // K: 4608*128 elems, 8 per thread
        int i = (bx - 2304) * 256 + t;      // [0, 73728)
        int g = i >> 4;
        short8 o;
        if (g < NUM_GENES) {
            const float4 k0 = *(const float4*)(key + (size_t)i * 8);
            const float4 k1 = *(const float4*)(key + (size_t)i * 8 + 4);
            o[0] = bf16bits(k0.x); o[1] = bf16bits(k0.y);
            o[2] = bf16bits(k0.z); o[3] = bf16bits(k0.w);
            o[4] = bf16bits(k1.x); o[5] = bf16bits(k1.y);
            o[6] = bf16bits(k1.z); o[7] = bf16bits(k1.w);
        } else {
#pragma unroll
            for (int j = 0; j < 8; ++j) o[j] = 0;
        }
        *(short8*)((short*)Kb + (size_t)i * 8) = o;
    } else {                                // zero: 18 blocks cover l,w (36864 floats each)
        int i = (bx - 2592) * 256 + t;      // [0, 4608)
        float4 z = {0.f, 0.f, 0.f, 0.f};
        *(float4*)(l + (size_t)i * 8) = z;
        *(float4*)(l + (size_t)i * 8 + 4) = z;
        *(float4*)(w + (size_t)i * 8) = z;
        *(float4*)(w + (size_t)i * 8 + 4) = z;
        if (bx == 2592) {
            if (t < 128) {                  // meanbuf: 1024 floats
                *(float4*)(meanbuf + t * 8) = z;
                *(float4*)(meanbuf + t * 8 + 4) = z;
            }
            if (t == 0) *donecnt = 0u;
        }
    }
}

// R5-VERBATIM phase kernel (62.6 us measured). Do not touch the loop shape:
// peeling the first MFMA (R6) or adding epilogue work (R6/R7) or merging
// stages (R8: VGPR spill) each regressed 30-400%.
// PB=false: resident=Q (per b), stream=K, out l[b,q] += rowsum(exp2(S))
// PB=true : resident=K, stream=Q (per b), out w[b,k] += rowsum(exp2(S)/l[q])
// A/B frag: lane holds row/col (lane&31), 16B at byte dsl*32 + (lane>>5)*16.
// C/D: col=lane&31, row=(r&3)+8*(r>>2)+4*(lane>>5).
template <bool PB>
__global__ __launch_bounds__(256)
void phase_kernel(const __hip_bfloat16* __restrict__ Qb,
                  const __hip_bfloat16* __restrict__ Kb,
                  const float* __restrict__ lsum,
                  float* __restrict__ out) {
    __shared__ __align__(16) char tile[2][32 * LDS_STRIDE];

    int rb    = blockIdx.x;   // resident 256-row block, 0..17
    int chunk = blockIdx.y;   // 0..5 over stream tiles
    int b     = blockIdx.z;   // batch

    const char* resident = (const char*)(PB ? Kb : (Qb + (size_t)b * GPAD * DM));
    const char* stream   = (const char*)(PB ? (Qb + (size_t)b * GPAD * DM) : Kb);

    int t = threadIdx.x;
    int lane = t & 63, wid = t >> 6;
    int m = lane & 31, half = lane >> 5;

    short8 afrag[2][8];
#pragma unroll
    for (int g = 0; g < 2; ++g) {
        const char* arow = resident + (size_t)(rb * 256 + wid * 64 + g * 32 + m) * ROWB;
#pragma unroll
        for (int dsl = 0; dsl < 8; ++dsl)
            afrag[g][dsl] = *(const short8*)(arow + dsl * 32 + half * 16);
    }

    float lacc[2][16];
#pragma unroll
    for (int g = 0; g < 2; ++g)
#pragma unroll
        for (int r = 0; r < 16; ++r) lacc[g][r] = 0.f;

    int t0 = chunk * TPC;
    int t1 = min(NTILES, t0 + TPC);
    int sr = t >> 3, sc = t & 7;   // staging: thread -> (row, 32B chunk)
    int soff = sr * LDS_STRIDE + sc * 32;

    {
        const char* src = stream + (size_t)(t0 * 32 + sr) * ROWB + sc * 32;
        float4 v0 = *(const float4*)src;
        float4 v1 = *(const float4*)(src + 16);
        *(float4*)(tile[0] + soff) = v0;
        *(float4*)(tile[0] + soff + 16) = v1;
    }

    int p = 0;
    for (int kt = t0; kt < t1; ++kt) {
        bool more = (kt + 1 < t1);
        float4 v0, v1;
        if (more) {   // next tile's global loads; latency hidden by MFMA below
            const char* s2 = stream + (size_t)((kt + 1) * 32 + sr) * ROWB + sc * 32;
            v0 = *(const float4*)s2;
            v1 = *(const float4*)(s2 + 16);
        }
        __syncthreads();   // buf[p] fully written; prior reads of buf[p^1] done

        floatx16 acc0, acc1;
#pragma unroll
        for (int r = 0; r < 16; ++r) { acc0[r] = 0.f; acc1[r] = 0.f; }
#pragma unroll
        for (int dsl = 0; dsl < 8; ++dsl) {
            short8 bfrag = *(const short8*)(tile[p] + m * LDS_STRIDE + dsl * 32 + half * 16);
            acc0 = __builtin_amdgcn_mfma_f32_32x32x16_bf16(afrag[0][dsl], bfrag, acc0, 0, 0, 0);
            acc1 = __builtin_amdgcn_mfma_f32_32x32x16_bf16(afrag[1][dsl], bfrag, acc1, 0, 0, 0);
        }

        if (more) {   // stage next tile into the other buffer
            *(float4*)(tile[p ^ 1] + soff) = v0;
            *(float4*)(tile[p ^ 1] + soff + 16) = v1;
        }

        if (PB) {
            float scl = __builtin_amdgcn_rcpf(lsum[b * GPAD + kt * 32 + m]);
#pragma unroll
            for (int r = 0; r < 16; ++r) {
                lacc[0][r] = fmaf(FAST_EXP2(acc0[r]), scl, lacc[0][r]);
                lacc[1][r] = fmaf(FAST_EXP2(acc1[r]), scl, lacc[1][r]);
            }
        } else {
#pragma unroll
            for (int r = 0; r < 16; ++r) {
                lacc[0][r] += FAST_EXP2(acc0[r]);
                lacc[1][r] += FAST_EXP2(acc1[r]);
            }
        }
        p ^= 1;
    }

#pragma unroll
    for (int off = 1; off <= 16; off <<= 1)
#pragma unroll
        for (int g = 0; g < 2; ++g)
#pragma unroll
            for (int r = 0; r < 16; ++r)
                lacc[g][r] += __shfl_xor(lacc[g][r], off, 64);

    if (m == 0) {   // lanes 0 and 32 hold sums for rows (+0 / +4); 32 atomics/block
#pragma unroll
        for (int g = 0; g < 2; ++g) {
            float* ob = out + b * GPAD + rb * 256 + wid * 64 + g * 32 + 4 * half;
#pragma unroll
            for (int r = 0; r < 16; ++r)
                atomicAdd(ob + (r & 3) + 8 * (r >> 2), lacc[g][r]);
        }
    }
}

// mean partials + last-block MLP (R7-verified tail pattern, in a light kernel).
// grid (35, 8), block 256.
__global__ __launch_bounds__(256)
void mean_mlp_k(const float* __restrict__ w, const float* __restrict__ V,
                const float* __restrict__ W1, const float* __restrict__ b1,
                const float* __restrict__ W2, const float* __restrict__ b2,
                float* __restrict__ meanbuf, float* __restrict__ out,
                unsigned* __restrict__ donecnt) {
    int rb = blockIdx.x, b = blockIdx.y;
    int t = threadIdx.x;
    int d = t & 127, half = t >> 7;        // each half-block covers 64 gene rows
    int g0 = rb * 128 + half * 64;
    int nv = NUM_GENES - g0;
    if (nv > 64) nv = 64;
    float a = 0.f;
    if (nv > 0) {
        const float* wb = w + b * GPAD + g0;
        const float* Vp = V + (size_t)g0 * 128 + d;
        for (int k = 0; k < nv; ++k)
            a += wb[k] * Vp[(size_t)k * 128];
        atomicAdd(meanbuf + b * 128 + d, a);
    }
    // last-block-done: the 280th block runs the MLP
    __shared__ int slast;
    __syncthreads();
    if (t == 0) {
        __threadfence();
        slast = (atomicAdd(donecnt, 1u) == MEAN_BLOCKS - 1u) ? 1 : 0;
    }
    __syncthreads();
    if (slast) {
        __threadfence();
        __shared__ float smean[1024];
        __shared__ float shh[512];
        for (int i = t; i < 1024; i += 256)
            smean[i] = __hip_atomic_load(meanbuf + i, __ATOMIC_RELAXED,
                                         __HIP_MEMORY_SCOPE_AGENT);
        __syncthreads();
        for (int pair = t; pair < 512; pair += 256) {
            int bb = pair >> 6, h = pair & 63;
            const float* mb = smean + bb * 128;
            float s = b1[h];
            for (int dd = 0; dd < 128; ++dd)
                s += (mb[dd] * (1.0f / 4384.0f)) * W1[dd * 64 + h];
            shh[pair] = 0.5f * s * (1.0f + erff(s * 0.70710678118654752f)); // exact gelu
        }
        __syncthreads();
        if (t < 208) {                  // 8 batches * 26 outputs
            int bb = t / 26, j = t % 26;
            const float* hp = shh + bb * 64;
            float o = b2[j];
            for (int k = 0; k < 64; ++k) o += hp[k] * W2[k * 26 + j];
            out[bb * 26 + j] = o;
        }
    }
}

extern "C" void kernel_launch(void* const* d_in, const int* in_sizes, int n_in,
                              void* d_out, int out_size, void* d_ws, size_t ws_size,
                              hipStream_t stream) {
    const float* mut  = (const float*)d_in[0];   // [8,4384,4]
    const float* V    = (const float*)d_in[1];   // [4384,128]
    const float* W_in = (const float*)d_in[2];   // [4,128]
    const float* b_in = (const float*)d_in[3];   // [128]
    const float* key  = (const float*)d_in[4];   // [4384,128]
    const float* W1   = (const float*)d_in[5];   // [128,64]
    const float* b1   = (const float*)d_in[6];   // [64]
    const float* W2   = (const float*)d_in[7];   // [64,26]
    const float* b2   = (const float*)d_in[8];   // [26]
    float* out = (float*)d_out;                  // [8,26]

    char* ws = (char*)d_ws;
    __hip_bfloat16* Qb = (__hip_bfloat16*)(ws);                    // 9,437,184
    __hip_bfloat16* Kb = (__hip_bfloat16*)(ws + 9437184);          // 1,179,648
    float* lbuf        = (float*)(ws + 10616832);                  //   147,456
    float* wbuf        = (float*)(ws + 10764288);                  //   147,456
    float* meanbuf     = (float*)(ws + 10911744);                  //     4,096
    unsigned* donecnt  = (unsigned*)(ws + 10915840);               //         4

    prep_all<<<2610, 256, 0, stream>>>(mut, W_in, b_in, key, Qb, Kb,
                                       lbuf, wbuf, meanbuf, donecnt);

    dim3 grid(RB_BLOCKS, NCHUNK, 8);
    phase_kernel<false><<<grid, 256, 0, stream>>>(Qb, Kb, lbuf, lbuf);  // l = rowsum exp2(S)
    phase_kernel<true><<<grid, 256, 0, stream>>>(Qb, Kb, lbuf, wbuf);   // w = colsum softmax

    mean_mlp_k<<<dim3(35, 8), 256, 0, stream>>>(wbuf, V, W1, b1, W2, b2,
                                                meanbuf, out, donecnt);
}